// Round 13
// baseline (113.945 us; speedup 1.0000x reference)
//
#include <hip/hip_runtime.h>

#define BB 4096
#define SS 200
#define DD 128
#define HH 64
#define NT 13            // 13 tiles of 16 rows (208 padded)
#define OUTW (DD + 1)

typedef __attribute__((ext_vector_type(4))) float f32x4;
typedef _Float16 f16x8 __attribute__((ext_vector_type(8)));

// DPP sum over each 16-lane group; all 16 lanes end with the group total.
template <int CTRL>
__device__ __forceinline__ float dpp_add(float x) {
  int xi = __float_as_int(x);
  int yi = __builtin_amdgcn_update_dpp(xi, xi, CTRL, 0xF, 0xF, false);
  return x + __int_as_float(yi);
}
__device__ __forceinline__ float row16_sum(float x) {
  x = dpp_add<0xB1>(x);    // quad_perm xor1
  x = dpp_add<0x4E>(x);    // quad_perm xor2
  x = dpp_add<0x124>(x);   // row_ror:4
  x = dpp_add<0x128>(x);   // row_ror:8
  return x;
}

// ---- setupA: Psw direct (pos@Wp -> f16 swizzled), Bfrag (We -> f16), mask probe ---
__global__ void setupA_kernel(const float* __restrict__ pos,
                              const float* __restrict__ Wp,
                              const float* __restrict__ We,
                              const void* __restrict__ maskv,
                              _Float16* __restrict__ Bfrag,
                              _Float16* __restrict__ Psw,
                              int* __restrict__ flag) {
  __shared__ int anyf[4];
  const int blk = blockIdx.x;
  const int t = threadIdx.x;
  if (blk < NT) {
    // Psw[((tile*2+half)*64+lane)*8 + e] = f16( P[s, h] ),
    //   ct=(half<<1)|(e>>2), r=e&3, s=tile*16+((lane>>4)<<2)+r (clamped), h=ct*16+(lane&15)
    const int tile = blk;
    for (int id = t; id < 1024; id += 256) {
      const int half = id >> 9;
      const int lane = (id >> 3) & 63;
      const int e = id & 7;
      const int ct = (half << 1) | (e >> 2);
      const int r = e & 3;
      int s = tile * 16 + ((lane >> 4) << 2) + r;
      if (s >= SS) s = SS - 1;
      const int h = ct * 16 + (lane & 15);
      const float* pr = pos + (size_t)s * DD;
      const float* wp = Wp + h;
      float a0 = 0.f, a1 = 0.f;
      #pragma unroll 8
      for (int d = 0; d < DD; d += 2) {
        a0 = fmaf(pr[d], wp[d * HH], a0);
        a1 = fmaf(pr[d + 1], wp[(d + 1) * HH], a1);
      }
      Psw[((size_t)(tile * 2 + half) * 64 + lane) * 8 + e] = (_Float16)(a0 + a1);
    }
  } else if (blk == NT) {
    // Bfrag[((ct*4+kt)*64+lane)*8 + j] = f16(We[kt*32 + 8*(lane>>4) + j][ct*16 + (lane&15)])
    for (int id = t; id < 1024; id += 256) {
      int lane = id & 63;
      int kt = (id >> 6) & 3;
      int ct = id >> 8;
      int kbase = kt * 32 + 8 * (lane >> 4);
      int n = ct * 16 + (lane & 15);
      _Float16* dst = Bfrag + id * 8;
      #pragma unroll
      for (int j = 0; j < 8; ++j) dst[j] = (_Float16)We[(kbase + j) * HH + n];
    }
  } else {
    // mask dtype probe: bool8 has nonzero bytes at positions %4!=0; int32(0/1) does not
    const unsigned char* mb = (const unsigned char*)maskv;
    int local = 0;
    for (int i = t; i < 4096; i += 256)
      if ((i & 3) != 0 && mb[i] != 0) local = 1;
    unsigned long long bal = __ballot(local != 0);
    if ((t & 63) == 0) anyf[t >> 6] = (bal != 0ull) ? 1 : 0;
    __syncthreads();
    if (t == 0) *flag = (anyf[0] | anyf[1] | anyf[2] | anyf[3]);
  }
}

// ---- setupB: c[b][h] = Xi[b].Wc[:,h]  +  packed mask bits per (b, lr) ------------
__global__ void setupB_kernel(const float* __restrict__ Xi,
                              const float* __restrict__ Wc,
                              const void* __restrict__ maskv,
                              const int* __restrict__ flagp,
                              float* __restrict__ cw,
                              unsigned short* __restrict__ mbitsArr) {
  const int t = threadIdx.x;
  const int w = t >> 6, lane = t & 63;
  const int base = blockIdx.x * 8;
  // c: wave w handles rows base+2w, base+2w+1
  {
    const int b0 = base + w * 2;
    const float* xi0 = Xi + (size_t)b0 * DD;
    const float* xi1 = xi0 + DD;
    const float* wc = Wc + lane;
    float a0 = 0.f, a1 = 0.f;
    #pragma unroll 8
    for (int d = 0; d < DD; ++d) {
      const float wv = wc[d * HH];
      a0 = fmaf(xi0[d], wv, a0);
      a1 = fmaf(xi1[d], wv, a1);
    }
    cw[(size_t)b0 * HH + lane] = a0;
    cw[(size_t)(b0 + 1) * HH + lane] = a1;
  }
  // mbits: threads 0..127 -> (row t>>4 of this block's 8, lr = t&15)
  if (t < 128) {
    const int b = base + (t >> 4);
    const int lr = t & 15;
    const int mflag = *flagp;
    unsigned mb = 0;
    if (mflag) {
      const unsigned char* mbp = (const unsigned char*)maskv + (size_t)b * SS;
      #pragma unroll
      for (int tt = 0; tt < NT; ++tt) {
        const int srow = tt * 16 + lr;
        unsigned v = (srow < SS) ? (unsigned)mbp[srow] : 0u;
        mb |= (v ? 1u : 0u) << tt;
      }
    } else {
      const int* mip = (const int*)maskv + (size_t)b * SS;
      #pragma unroll
      for (int tt = 0; tt < NT; ++tt) {
        const int srow = tt * 16 + lr;
        unsigned v = (srow < SS) ? (unsigned)(mip[srow] != 0) : 0u;
        mb |= v << tt;
      }
    }
    mbitsArr[(size_t)b * 16 + lr] = (unsigned short)mb;
  }
}

// ----- fused: 4 waves/block (2 blocks/CU), wave = row, r12 schedule, no barriers ---
__global__ __launch_bounds__(256, 2) void fused_kernel(
    const float* __restrict__ Xs,
    const float* __restrict__ zv, const float* __restrict__ cw,
    const unsigned short* __restrict__ mbitsArr,
    const _Float16* __restrict__ Comb,   // Bfrag (8192 f16) + Psw (13312 f16)
    float* __restrict__ out) {
  __shared__ __align__(16) float xlds[4][2][2048];       // 64 KB: per-wave X dbuf

  const int t = threadIdx.x;
  const int lane = t & 63;
  const int w = t >> 6;                 // 0..3
  const int lg = lane >> 4;
  const int lr = lane & 15;
  const int b = blockIdx.x * 4 + w;

  const float* Xrow = Xs + (size_t)b * (SS * DD);
  const f16x8* pswb = (const f16x8*)(Comb + 8192);

  // stage tile tt into wave-private buffer: 8 x global_load_lds, each a CONTIGUOUS
  // 1KB; source chunk pre-swizzled (c ^ row, involution) for bank-balanced ds_read.
  auto stage_tile = [&](int tt, int buf) {
    float* dst = &xlds[w][buf][0];
    #pragma unroll
    for (int k = 0; k < 8; ++k) {
      const int row = 2 * k + (lane >> 5);              // local row 0..15
      int grow = tt * 16 + row; if (grow >= SS) grow = SS - 1;  // clamped rows masked
      const int c = (lane & 31) ^ row;                  // source 16B-chunk index
      const float* src = Xrow + (size_t)grow * DD + c * 4;
      __builtin_amdgcn_global_load_lds(
          (const __attribute__((address_space(1))) void*)src,
          (__attribute__((address_space(3))) void*)(dst + k * 256),
          16, 0, 0);
    }
  };

  // ---- prologue: issue tile-0 stage + P(0) prefetch first ----
  stage_tile(0, 0);
  f16x8 pn0 = pswb[lane];
  f16x8 pn1 = pswb[64 + lane];

  // ---- Bfrag -> registers (16 KB, L2/L3-hot) ----
  f16x8 bfr[16];
  {
    const f16x8* bg = (const f16x8*)Comb;
    #pragma unroll
    for (int i = 0; i < 16; ++i) bfr[i] = bg[i * 64 + lane];
  }

  // ---- c4/z4: direct loads; mbits: single precomputed ushort ----
  float c4[4], z4[4];
  #pragma unroll
  for (int ct = 0; ct < 4; ++ct) {
    c4[ct] = cw[(size_t)b * HH + ct * 16 + lr];
    z4[ct] = zv[ct * 16 + lr];
  }
  const unsigned mbits = mbitsArr[(size_t)b * 16 + lr];
  // NO __syncthreads anywhere: xlds is wave-private, Bfrag in regs.

  float part[4][8];
  #pragma unroll
  for (int kt = 0; kt < 4; ++kt)
    #pragma unroll
    for (int j = 0; j < 8; ++j) part[kt][j] = 0.f;
  float usum = 0.f, ssum = 0.f;
  int cur = 0;

  for (int tt = 0; tt < NT; ++tt) {
    // ---- all in-flight VMEM belongs to tile tt (or earlier): drain once ----
    asm volatile("s_waitcnt vmcnt(0)" ::: "memory");
    __builtin_amdgcn_sched_barrier(0);
    // consume P regs into acc init, then reuse them for the t+1 prefetch
    f32x4 acc[4];
    #pragma unroll
    for (int ct = 0; ct < 4; ++ct) {
      #pragma unroll
      for (int r = 0; r < 4; ++r) {
        const float pv = (ct < 2) ? (float)pn0[ct * 4 + r] : (float)pn1[(ct - 2) * 4 + r];
        acc[ct][r] = pv + c4[ct];
      }
    }
    // ---- issue tile t+1 stage + P(t+1) (consumed only next iteration) ----
    if (tt + 1 < NT) {
      stage_tile(tt + 1, cur ^ 1);
      pn0 = pswb[(tt + 1) * 128 + lane];
      pn1 = pswb[(tt + 1) * 128 + 64 + lane];
    }
    // ---- ds_read fragments from buf[cur] (swizzled chunks, bank-balanced) ----
    const float* bufp = &xlds[w][cur][0];
    f16x8 af[4];
    #pragma unroll
    for (int kt = 0; kt < 4; ++kt) {
      const int ch = lg * 2 + kt * 8;
      const f32x4 v0 = *(const f32x4*)&bufp[lr * 128 + (((ch    ) ^ lr) * 4)];
      const f32x4 v1 = *(const f32x4*)&bufp[lr * 128 + (((ch + 1) ^ lr) * 4)];
      f16x8 v;
      v[0] = (_Float16)v0[0]; v[1] = (_Float16)v0[1];
      v[2] = (_Float16)v0[2]; v[3] = (_Float16)v0[3];
      v[4] = (_Float16)v1[0]; v[5] = (_Float16)v1[1];
      v[6] = (_Float16)v1[2]; v[7] = (_Float16)v1[3];
      af[kt] = v;
    }
    #pragma unroll
    for (int kt = 0; kt < 4; ++kt)
      #pragma unroll
      for (int ct = 0; ct < 4; ++ct)
        acc[ct] = __builtin_amdgcn_mfma_f32_16x16x32_f16(af[kt], bfr[ct * 4 + kt], acc[ct], 0, 0, 0);
    // scores[s=tt*16+4lg+r] = sum_h z[h]*tanh(pre); DPP row-sum over the 16 lr lanes
    float sc[4];
    #pragma unroll
    for (int r = 0; r < 4; ++r) {
      float p = 0.f;
      #pragma unroll
      for (int ct = 0; ct < 4; ++ct) {
        const float e2 = __expf(2.f * acc[ct][r]);
        const float th = 1.f - 2.f * __builtin_amdgcn_rcpf(e2 + 1.f);
        p = fmaf(z4[ct], th, p);
      }
      sc[r] = row16_sum(p);       // all 16 lanes of group lg hold score(s=tt*16+4lg+r)
    }
    // redistribute: lane (lg,lr) needs score of row tt*16+lr (held by group lr>>2)
    const float s01 = (lr & 1) ? sc[1] : sc[0];
    const float s23 = (lr & 1) ? sc[3] : sc[2];
    const float sel = (lr & 2) ? s23 : s01;
    const float mysc = __shfl(sel, ((lr >> 2) << 4) | lr, 64);
    const bool mv = (mbits >> tt) & 1u;
    const float u = mv ? __expf(mysc) : 0.f;    // |score| <= sum|z| ~ 7: no max-sub needed
    ssum += mv ? mysc : 0.f;
    usum += u;
    #pragma unroll
    for (int kt = 0; kt < 4; ++kt)
      #pragma unroll
      for (int j = 0; j < 8; ++j)
        part[kt][j] = fmaf(u, (float)af[kt][j], part[kt][j]);
    cur ^= 1;
  }

  // ---- reduce over the 16 lr lanes (rows) via DPP; each lg group = distinct cols ----
  #pragma unroll
  for (int kt = 0; kt < 4; ++kt)
    #pragma unroll
    for (int j = 0; j < 8; ++j)
      part[kt][j] = row16_sum(part[kt][j]);
  usum = row16_sum(usum);
  ssum = row16_sum(ssum);

  const float inv = 1.f / usum;
  if (lr == 0) {
    float* ob = out + (size_t)b * OUTW;
    #pragma unroll
    for (int kt = 0; kt < 4; ++kt)
      #pragma unroll
      for (int j = 0; j < 8; ++j)
        ob[kt * 32 + lg * 8 + j] = part[kt][j] * inv;
  }
  if (lane == 8) out[(size_t)b * OUTW + DD] = ssum;
}

extern "C" void kernel_launch(void* const* d_in, const int* in_sizes, int n_in,
                              void* d_out, int out_size, void* d_ws, size_t ws_size,
                              hipStream_t stream) {
  const float* Xs  = (const float*)d_in[0];   // X_series [B,S,D]
  const float* pos = (const float*)d_in[1];   // pos_series [S,D]
  const float* Xi  = (const float*)d_in[2];   // X_item [B,D]
  const void*  mk  = d_in[3];                 // valid_mask [B,S] (bool8 or int32 — probed)
  const float* Wc  = (const float*)d_in[4];
  const float* Wp  = (const float*)d_in[5];
  const float* We  = (const float*)d_in[6];
  const float* zv  = (const float*)d_in[7];
  float* out = (float*)d_out;

  char* ws = (char*)d_ws;
  int*            flag  = (int*)ws;                          // 4 B      @ 0
  _Float16*       Bfrag = (_Float16*)(ws + 256);             // 16384 B  @ 256
  _Float16*       Psw   = (_Float16*)(ws + 256 + 16384);     // 26624 B  @ 16640 (contig!)
  float*          cw    = (float*)(ws + 43520);              // 1 MiB    @ 43520
  unsigned short* mbA   = (unsigned short*)(ws + 43520 + (size_t)BB * HH * 4); // 128 KiB

  setupA_kernel<<<NT + 2, 256, 0, stream>>>(pos, Wp, We, mk, Bfrag, Psw, flag);
  setupB_kernel<<<BB / 8, 256, 0, stream>>>(Xi, Wc, mk, flag, cw, mbA);
  fused_kernel<<<BB / 4, 256, 0, stream>>>(Xs, zv, cw, mbA, Bfrag, out);
}

// Round 14
// 95.332 us; speedup vs baseline: 1.1952x; 1.1952x over previous
//
#include <hip/hip_runtime.h>

#define BB 4096
#define SS 200
#define DD 128
#define HH 64
#define NT 13            // 13 tiles of 16 rows (208 padded)
#define OUTW (DD + 1)

typedef __attribute__((ext_vector_type(4))) float f32x4;
typedef _Float16 f16x8 __attribute__((ext_vector_type(8)));

// DPP sum over each 16-lane group; all 16 lanes end with the group total.
template <int CTRL>
__device__ __forceinline__ float dpp_add(float x) {
  int xi = __float_as_int(x);
  int yi = __builtin_amdgcn_update_dpp(xi, xi, CTRL, 0xF, 0xF, false);
  return x + __int_as_float(yi);
}
__device__ __forceinline__ float row16_sum(float x) {
  x = dpp_add<0xB1>(x);    // quad_perm xor1
  x = dpp_add<0x4E>(x);    // quad_perm xor2
  x = dpp_add<0x124>(x);   // row_ror:4
  x = dpp_add<0x128>(x);   // row_ror:8
  return x;
}

// ------ setup1 (wide): Pmat = pos@Wp, Bfrag, mask probe, c = Xi@Wc  (r12 verbatim) -
__global__ void setup_kernel(const float* __restrict__ pos,
                             const float* __restrict__ Wp,
                             const float* __restrict__ We,
                             const void* __restrict__ maskv,
                             const float* __restrict__ Xi,
                             const float* __restrict__ Wc,
                             float* __restrict__ Pmat,
                             _Float16* __restrict__ Bfrag,
                             float* __restrict__ cw,
                             int* __restrict__ flag) {
  __shared__ int anyf[4];
  const int blk = blockIdx.x;
  const int t = threadIdx.x;
  if (blk < SS) {
    if (t < HH) {
      float acc = 0.f;
      #pragma unroll 8
      for (int d = 0; d < DD; ++d) acc = fmaf(pos[blk * DD + d], Wp[d * HH + t], acc);
      Pmat[blk * HH + t] = acc;
    }
  } else if (blk == SS) {
    // Bfrag[((ct*4+kt)*64+lane)*8 + j] = f16(We[kt*32 + 8*(lane>>4) + j][ct*16 + (lane&15)])
    for (int id = t; id < 1024; id += 256) {
      int lane = id & 63;
      int kt = (id >> 6) & 3;
      int ct = id >> 8;
      int kbase = kt * 32 + 8 * (lane >> 4);
      int n = ct * 16 + (lane & 15);
      _Float16* dst = Bfrag + id * 8;
      #pragma unroll
      for (int j = 0; j < 8; ++j) dst[j] = (_Float16)We[(kbase + j) * HH + n];
    }
  } else if (blk == SS + 1) {
    // mask dtype probe: bool8 has nonzero bytes at positions %4!=0; int32(0/1) does not
    const unsigned char* mb = (const unsigned char*)maskv;
    int local = 0;
    for (int i = t; i < 4096; i += 256)
      if ((i & 3) != 0 && mb[i] != 0) local = 1;
    unsigned long long bal = __ballot(local != 0);
    if ((t & 63) == 0) anyf[t >> 6] = (bal != 0ull) ? 1 : 0;
    __syncthreads();
    if (t == 0) *flag = (anyf[0] | anyf[1] | anyf[2] | anyf[3]);
  } else {
    // c precompute: 4 waves x 2 rows each; cw[b][h] = Xi[b] . Wc[:,h]
    const int w = t >> 6, lane = t & 63;
    const int base = (blk - (SS + 2)) * 8 + w * 2;
    const float* xi0 = Xi + (size_t)base * DD;
    const float* xi1 = xi0 + DD;
    const float* wc = Wc + lane;
    float a0 = 0.f, a1 = 0.f;
    #pragma unroll 8
    for (int d = 0; d < DD; ++d) {
      const float wv = wc[d * HH];
      a0 = fmaf(xi0[d], wv, a0);
      a1 = fmaf(xi1[d], wv, a1);
    }
    cw[(size_t)base * HH + lane] = a0;
    cw[(size_t)(base + 1) * HH + lane] = a1;
  }
}

// ------ setup2 (wide): Psw swizzle (13 blocks) + mbits precompute (512 blocks) -----
__global__ void setup2_kernel(const float* __restrict__ Pmat,
                              const void* __restrict__ maskv,
                              const int* __restrict__ flagp,
                              _Float16* __restrict__ Psw,
                              unsigned short* __restrict__ mbitsArr) {
  const int blk = blockIdx.x;
  const int t = threadIdx.x;
  if (blk < NT) {
    // Psw[((tile*2+half)*64+lane)*8+e] = f16(P[tile*16+((lane>>4)<<2)+(e&3),
    //                                          ((half<<1)|(e>>2))*16+(lane&15)])
    const int tile = blk;
    for (int id = t; id < 1024; id += 256) {
      const int half = id >> 9;
      const int lane = (id >> 3) & 63;
      const int e = id & 7;
      const int ct = (half << 1) | (e >> 2);
      const int r = e & 3;
      int s = tile * 16 + ((lane >> 4) << 2) + r;
      if (s >= SS) s = SS - 1;
      Psw[((size_t)(tile * 2 + half) * 64 + lane) * 8 + e] =
          (_Float16)Pmat[s * HH + ct * 16 + (lane & 15)];
    }
  } else {
    // mbits: block handles 8 batch rows; threads 0..127 -> (row t>>4, lr t&15)
    const int base = (blk - NT) * 8;
    if (t < 128) {
      const int b = base + (t >> 4);
      const int lr = t & 15;
      const int mflag = *flagp;
      unsigned mb = 0;
      if (mflag) {
        const unsigned char* mbp = (const unsigned char*)maskv + (size_t)b * SS;
        #pragma unroll
        for (int tt = 0; tt < NT; ++tt) {
          const int srow = tt * 16 + lr;
          unsigned v = (srow < SS) ? (unsigned)mbp[srow] : 0u;
          mb |= (v ? 1u : 0u) << tt;
        }
      } else {
        const int* mip = (const int*)maskv + (size_t)b * SS;
        #pragma unroll
        for (int tt = 0; tt < NT; ++tt) {
          const int srow = tt * 16 + lr;
          unsigned v = (srow < SS) ? (unsigned)(mip[srow] != 0) : 0u;
          mb |= v << tt;
        }
      }
      mbitsArr[(size_t)b * 16 + lr] = (unsigned short)mb;
    }
  }
}

// ----- fused: 4 waves/block (2 blocks/CU), wave = row, r12 schedule, no barriers ---
__global__ __launch_bounds__(256, 2) void fused_kernel(
    const float* __restrict__ Xs,
    const float* __restrict__ zv, const float* __restrict__ cw,
    const unsigned short* __restrict__ mbitsArr,
    const _Float16* __restrict__ Comb,   // Bfrag (8192 f16) + Psw (13312 f16)
    float* __restrict__ out) {
  __shared__ __align__(16) float xlds[4][2][2048];       // 64 KB: per-wave X dbuf

  const int t = threadIdx.x;
  const int lane = t & 63;
  const int w = t >> 6;                 // 0..3
  const int lg = lane >> 4;
  const int lr = lane & 15;
  const int b = blockIdx.x * 4 + w;

  const float* Xrow = Xs + (size_t)b * (SS * DD);
  const f16x8* pswb = (const f16x8*)(Comb + 8192);

  // stage tile tt into wave-private buffer: 8 x global_load_lds, each a CONTIGUOUS
  // 1KB; source chunk pre-swizzled (c ^ row, involution) for bank-balanced ds_read.
  auto stage_tile = [&](int tt, int buf) {
    float* dst = &xlds[w][buf][0];
    #pragma unroll
    for (int k = 0; k < 8; ++k) {
      const int row = 2 * k + (lane >> 5);              // local row 0..15
      int grow = tt * 16 + row; if (grow >= SS) grow = SS - 1;  // clamped rows masked
      const int c = (lane & 31) ^ row;                  // source 16B-chunk index
      const float* src = Xrow + (size_t)grow * DD + c * 4;
      __builtin_amdgcn_global_load_lds(
          (const __attribute__((address_space(1))) void*)src,
          (__attribute__((address_space(3))) void*)(dst + k * 256),
          16, 0, 0);
    }
  };

  // ---- prologue: issue tile-0 stage + P(0) prefetch first ----
  stage_tile(0, 0);
  f16x8 pn0 = pswb[lane];
  f16x8 pn1 = pswb[64 + lane];

  // ---- Bfrag -> registers (16 KB, L2/L3-hot) ----
  f16x8 bfr[16];
  {
    const f16x8* bg = (const f16x8*)Comb;
    #pragma unroll
    for (int i = 0; i < 16; ++i) bfr[i] = bg[i * 64 + lane];
  }

  // ---- c4/z4: direct loads; mbits: single precomputed ushort ----
  float c4[4], z4[4];
  #pragma unroll
  for (int ct = 0; ct < 4; ++ct) {
    c4[ct] = cw[(size_t)b * HH + ct * 16 + lr];
    z4[ct] = zv[ct * 16 + lr];
  }
  const unsigned mbits = mbitsArr[(size_t)b * 16 + lr];
  // NO __syncthreads anywhere: xlds is wave-private, Bfrag in regs.

  float part[4][8];
  #pragma unroll
  for (int kt = 0; kt < 4; ++kt)
    #pragma unroll
    for (int j = 0; j < 8; ++j) part[kt][j] = 0.f;
  float usum = 0.f, ssum = 0.f;
  int cur = 0;

  for (int tt = 0; tt < NT; ++tt) {
    // ---- all in-flight VMEM belongs to tile tt (or earlier): drain once ----
    asm volatile("s_waitcnt vmcnt(0)" ::: "memory");
    __builtin_amdgcn_sched_barrier(0);
    // consume P regs into acc init, then reuse them for the t+1 prefetch
    f32x4 acc[4];
    #pragma unroll
    for (int ct = 0; ct < 4; ++ct) {
      #pragma unroll
      for (int r = 0; r < 4; ++r) {
        const float pv = (ct < 2) ? (float)pn0[ct * 4 + r] : (float)pn1[(ct - 2) * 4 + r];
        acc[ct][r] = pv + c4[ct];
      }
    }
    // ---- issue tile t+1 stage + P(t+1) (consumed only next iteration) ----
    if (tt + 1 < NT) {
      stage_tile(tt + 1, cur ^ 1);
      pn0 = pswb[(tt + 1) * 128 + lane];
      pn1 = pswb[(tt + 1) * 128 + 64 + lane];
    }
    // ---- ds_read fragments from buf[cur] (swizzled chunks, bank-balanced) ----
    const float* bufp = &xlds[w][cur][0];
    f16x8 af[4];
    #pragma unroll
    for (int kt = 0; kt < 4; ++kt) {
      const int ch = lg * 2 + kt * 8;
      const f32x4 v0 = *(const f32x4*)&bufp[lr * 128 + (((ch    ) ^ lr) * 4)];
      const f32x4 v1 = *(const f32x4*)&bufp[lr * 128 + (((ch + 1) ^ lr) * 4)];
      f16x8 v;
      v[0] = (_Float16)v0[0]; v[1] = (_Float16)v0[1];
      v[2] = (_Float16)v0[2]; v[3] = (_Float16)v0[3];
      v[4] = (_Float16)v1[0]; v[5] = (_Float16)v1[1];
      v[6] = (_Float16)v1[2]; v[7] = (_Float16)v1[3];
      af[kt] = v;
    }
    #pragma unroll
    for (int kt = 0; kt < 4; ++kt)
      #pragma unroll
      for (int ct = 0; ct < 4; ++ct)
        acc[ct] = __builtin_amdgcn_mfma_f32_16x16x32_f16(af[kt], bfr[ct * 4 + kt], acc[ct], 0, 0, 0);
    // scores[s=tt*16+4lg+r] = sum_h z[h]*tanh(pre); DPP row-sum over the 16 lr lanes
    float sc[4];
    #pragma unroll
    for (int r = 0; r < 4; ++r) {
      float p = 0.f;
      #pragma unroll
      for (int ct = 0; ct < 4; ++ct) {
        const float e2 = __expf(2.f * acc[ct][r]);
        const float th = 1.f - 2.f * __builtin_amdgcn_rcpf(e2 + 1.f);
        p = fmaf(z4[ct], th, p);
      }
      sc[r] = row16_sum(p);       // all 16 lanes of group lg hold score(s=tt*16+4lg+r)
    }
    // redistribute: lane (lg,lr) needs score of row tt*16+lr (held by group lr>>2)
    const float s01 = (lr & 1) ? sc[1] : sc[0];
    const float s23 = (lr & 1) ? sc[3] : sc[2];
    const float sel = (lr & 2) ? s23 : s01;
    const float mysc = __shfl(sel, ((lr >> 2) << 4) | lr, 64);
    const bool mv = (mbits >> tt) & 1u;
    const float u = mv ? __expf(mysc) : 0.f;    // |score| <= sum|z| ~ 7: no max-sub needed
    ssum += mv ? mysc : 0.f;
    usum += u;
    #pragma unroll
    for (int kt = 0; kt < 4; ++kt)
      #pragma unroll
      for (int j = 0; j < 8; ++j)
        part[kt][j] = fmaf(u, (float)af[kt][j], part[kt][j]);
    cur ^= 1;
  }

  // ---- reduce over the 16 lr lanes (rows) via DPP; each lg group = distinct cols ----
  #pragma unroll
  for (int kt = 0; kt < 4; ++kt)
    #pragma unroll
    for (int j = 0; j < 8; ++j)
      part[kt][j] = row16_sum(part[kt][j]);
  usum = row16_sum(usum);
  ssum = row16_sum(ssum);

  const float inv = 1.f / usum;
  if (lr == 0) {
    float* ob = out + (size_t)b * OUTW;
    #pragma unroll
    for (int kt = 0; kt < 4; ++kt)
      #pragma unroll
      for (int j = 0; j < 8; ++j)
        ob[kt * 32 + lg * 8 + j] = part[kt][j] * inv;
  }
  if (lane == 8) out[(size_t)b * OUTW + DD] = ssum;
}

extern "C" void kernel_launch(void* const* d_in, const int* in_sizes, int n_in,
                              void* d_out, int out_size, void* d_ws, size_t ws_size,
                              hipStream_t stream) {
  const float* Xs  = (const float*)d_in[0];   // X_series [B,S,D]
  const float* pos = (const float*)d_in[1];   // pos_series [S,D]
  const float* Xi  = (const float*)d_in[2];   // X_item [B,D]
  const void*  mk  = d_in[3];                 // valid_mask [B,S] (bool8 or int32 — probed)
  const float* Wc  = (const float*)d_in[4];
  const float* Wp  = (const float*)d_in[5];
  const float* We  = (const float*)d_in[6];
  const float* zv  = (const float*)d_in[7];
  float* out = (float*)d_out;

  char* ws = (char*)d_ws;
  int*            flag  = (int*)ws;                              // 4 B     @ 0
  float*          Pmat  = (float*)(ws + 256);                    // 51200 B @ 256
  _Float16*       Bfrag = (_Float16*)(ws + 256 + SS * HH * 4);   // 16384 B @ 51456
  _Float16*       Psw   = (_Float16*)(ws + 67840);               // 26624 B @ 67840 (contig w/ Bfrag)
  float*          cw    = (float*)(ws + 94464);                  // 1 MiB   @ 94464
  unsigned short* mbA   = (unsigned short*)(ws + 94464 + (size_t)BB * HH * 4); // 128 KiB

  setup_kernel<<<SS + 2 + BB / 8, 256, 0, stream>>>(pos, Wp, We, mk, Xi, Wc,
                                                    Pmat, Bfrag, cw, flag);
  setup2_kernel<<<NT + BB / 8, 256, 0, stream>>>(Pmat, mk, flag, Psw, mbA);
  fused_kernel<<<BB / 4, 256, 0, stream>>>(Xs, zv, cw, mbA, Bfrag, out);
}